// Round 6
// baseline (481.061 us; speedup 1.0000x reference)
//
#include <hip/hip_runtime.h>
#include <hip/hip_bf16.h>

typedef __attribute__((ext_vector_type(8))) short bf16x8;   // 8 bf16 = 4 VGPRs
typedef __attribute__((ext_vector_type(4))) float f32x4;

#define D 128
#define P2CAP 8192

// ---------------- setup: zero bucket hist + cast x and all 6 weight matrices ----------------

__global__ __launch_bounds__(256) void k_setup(
    const float* __restrict__ x,
    const float* __restrict__ w0, const float* __restrict__ w1,
    const float* __restrict__ w2, const float* __restrict__ w3,
    const float* __restrict__ w4, const float* __restrict__ w5,
    __hip_bfloat16* __restrict__ xb, __hip_bfloat16* __restrict__ wb,
    int* __restrict__ bhist, int xpair)
{
    int t = blockIdx.x * 256 + threadIdx.x;
    if (t < 512) bhist[t] = 0;
    if (t < xpair) {
        float2 f = ((const float2*)x)[t];
        ((__hip_bfloat162*)xb)[t] = __float22bfloat162_rn(f);
    }
    if (t < 6 * 8192) {                      // 6 matrices x 8192 float2 pairs
        int wsel = t >> 13, wi = t & 8191;
        const float* wp = w0;
        if (wsel == 1) wp = w1;
        else if (wsel == 2) wp = w2;
        else if (wsel == 3) wp = w3;
        else if (wsel == 4) wp = w4;
        else if (wsel == 5) wp = w5;
        float2 f = ((const float2*)wp)[wi];
        ((__hip_bfloat162*)wb)[t] = __float22bfloat162_rn(f);
    }
}

// ---------------- CSR build: 2-level bucket counting sort ----------------
// bucket = dst >> 8 (256 nodes per bucket)

__global__ __launch_bounds__(256) void k_p0(const int* __restrict__ dst,
                                            int* __restrict__ bhist, int e, int n, int epb) {
    __shared__ int lh[512];
    for (int i = threadIdx.x; i < 512; i += 256) lh[i] = 0;
    __syncthreads();
    int lo = blockIdx.x * epb;
    int hi = lo + epb; if (hi > e) hi = e;
    for (int i = lo + threadIdx.x; i < hi; i += 256) {
        int d = dst[i]; d = ((unsigned)d < (unsigned)n) ? d : 0;
        atomicAdd(&lh[d >> 8], 1);
    }
    __syncthreads();
    for (int i = threadIdx.x; i < 512; i += 256)
        if (lh[i]) atomicAdd(&bhist[i], lh[i]);
}

__global__ void k_bscan(const int* __restrict__ bhist, int* __restrict__ bbase,
                        int* __restrict__ bcursor, int nb) {
    __shared__ int lds[512];
    int t = threadIdx.x;
    int v = (t < nb) ? bhist[t] : 0;
    lds[t] = v;
    __syncthreads();
    for (int off = 1; off < 512; off <<= 1) {
        int x = (t >= off) ? lds[t - off] : 0;
        __syncthreads();
        lds[t] += x;
        __syncthreads();
    }
    if (t < nb) { int b = lds[t] - v; bbase[t] = b; bcursor[t] = b; }
    if (t == nb) bbase[t] = lds[nb - 1];     // total
}

__global__ __launch_bounds__(256) void k_p1(const int* __restrict__ src,
                                            const int* __restrict__ dst,
                                            int* __restrict__ bcursor,
                                            int* __restrict__ tmp, int e, int n, int epb) {
    __shared__ int lh[512], gb[512];
    for (int i = threadIdx.x; i < 512; i += 256) lh[i] = 0;
    __syncthreads();
    int lo = blockIdx.x * epb;
    int hi = lo + epb; if (hi > e) hi = e;
    for (int i = lo + threadIdx.x; i < hi; i += 256) {
        int d = dst[i]; d = ((unsigned)d < (unsigned)n) ? d : 0;
        atomicAdd(&lh[d >> 8], 1);
    }
    __syncthreads();
    for (int i = threadIdx.x; i < 512; i += 256) {
        int c = lh[i];
        gb[i] = c ? atomicAdd(&bcursor[i], c) : 0;
    }
    __syncthreads();
    for (int i = threadIdx.x; i < 512; i += 256) lh[i] = 0;  // reuse as local cursor
    __syncthreads();
    for (int i = lo + threadIdx.x; i < hi; i += 256) {
        int d = dst[i]; d = ((unsigned)d < (unsigned)n) ? d : 0;
        int s = src[i]; s = ((unsigned)s < (unsigned)n) ? s : 0;
        int b = d >> 8;
        int p = gb[b] + atomicAdd(&lh[b], 1);
        tmp[p] = s | ((d & 255) << 17);      // src < 2^17, dlow in bits 17..24
    }
}

__global__ __launch_bounds__(256) void k_p2(const int* __restrict__ tmp,
                                            const int* __restrict__ bbase,
                                            int* __restrict__ deg, int* __restrict__ offs,
                                            int* __restrict__ csr, int n) {
    __shared__ int hist[256], loc[256], cur[256];
    __shared__ int out[P2CAP];
    int b = blockIdx.x, t = threadIdx.x;
    int base = bbase[b];
    int cnt = bbase[b + 1] - base;
    int nodes = n - b * 256; if (nodes > 256) nodes = 256;
    hist[t] = 0;
    __syncthreads();
    for (int i = t; i < cnt; i += 256)
        atomicAdd(&hist[(tmp[base + i] >> 17) & 255], 1);
    __syncthreads();
    int v = hist[t];
    loc[t] = v;
    __syncthreads();
    for (int off = 1; off < 256; off <<= 1) {
        int x = (t >= off) ? loc[t - off] : 0;
        __syncthreads();
        loc[t] += x;
        __syncthreads();
    }
    int myloc = loc[t] - v;                  // exclusive
    cur[t] = myloc;
    if (t < nodes) { deg[b * 256 + t] = v; offs[b * 256 + t] = base + myloc; }
    __syncthreads();
    if (cnt <= P2CAP) {
        for (int i = t; i < cnt; i += 256) {
            int e = tmp[base + i];
            int p = atomicAdd(&cur[(e >> 17) & 255], 1);
            out[p] = e & 0x1FFFF;
        }
        __syncthreads();
        for (int i = t; i < cnt; i += 256) csr[base + i] = out[i];   // coalesced
    } else {                                  // slow-path fallback (never for uniform edges)
        for (int i = t; i < cnt; i += 256) {
            int e = tmp[base + i];
            int p = atomicAdd(&cur[(e >> 17) & 255], 1);
            csr[base + p] = e & 0x1FFFF;
        }
    }
}

// ---------------- mean aggregation: wave per node, 4 edges in flight,
// 16 lanes x 16B per edge row, 8 fp32 accumulators per lane ----------------

__global__ __launch_bounds__(256) void k_agg(
    const __hip_bfloat16* __restrict__ h,      // [n, 128]
    const int* __restrict__ csr,
    const int* __restrict__ offs,
    const int* __restrict__ deg,
    __hip_bfloat16* __restrict__ mean,         // [n, 128]
    int n)
{
    int node = blockIdx.x * 4 + (threadIdx.x >> 6);
    int lane = threadIdx.x & 63;
    if (node >= n) return;
    int grp = lane >> 4;                       // edge slot 0..3
    int sub = lane & 15;                       // 16B chunk within the 256B row
    int start = offs[node];
    int cnt = deg[node];

    float acc[8];
    #pragma unroll
    for (int k = 0; k < 8; ++k) acc[k] = 0.f;

    const char* hb = (const char*)h;
    for (int i = 0; i < cnt; i += 4) {
        int e = i + grp;
        int ec = (e < cnt) ? e : (cnt - 1);    // clamp for valid address
        int s = csr[start + ec];
        s = ((unsigned)s < (unsigned)n) ? s : 0;
        int4 d = *(const int4*)(hb + (size_t)s * 256 + sub * 16);
        if (e >= cnt) { d.x = 0; d.y = 0; d.z = 0; d.w = 0; }   // mask tail
        // unpack bf16 pairs -> fp32 accumulate (lo = <<16, hi = &0xffff0000)
        acc[0] += __uint_as_float((unsigned)d.x << 16);
        acc[1] += __uint_as_float((unsigned)d.x & 0xffff0000u);
        acc[2] += __uint_as_float((unsigned)d.y << 16);
        acc[3] += __uint_as_float((unsigned)d.y & 0xffff0000u);
        acc[4] += __uint_as_float((unsigned)d.z << 16);
        acc[5] += __uint_as_float((unsigned)d.z & 0xffff0000u);
        acc[6] += __uint_as_float((unsigned)d.w << 16);
        acc[7] += __uint_as_float((unsigned)d.w & 0xffff0000u);
    }

    // reduce across the 4 edge groups (lanes differing in bits 4..5)
    #pragma unroll
    for (int k = 0; k < 8; ++k) {
        acc[k] += __shfl_xor(acc[k], 16);
        acc[k] += __shfl_xor(acc[k], 32);
    }

    if (grp == 0) {
        float inv = 1.0f / fmaxf((float)cnt, 1.0f);
        union { int4 i4; __hip_bfloat162 h2[4]; } u;
        #pragma unroll
        for (int k = 0; k < 4; ++k)
            u.h2[k] = __float22bfloat162_rn(make_float2(acc[2 * k] * inv, acc[2 * k + 1] * inv));
        *(int4*)((char*)mean + (size_t)node * 256 + sub * 16) = u.i4;
    }
}

// ---------------- fused GEMM: out = act([mean|h] @ [Wl|Wr]^T + b) ----------------
// Block: 256 threads = 4 waves, M-tile = 256 rows (64/wave = 4 MFMA row-tiles).
// W (both halves, 64 KB) in LDS, XOR-swizzled 16B chunks; each B-fragment
// LDS read feeds 4 MFMAs.

__global__ __launch_bounds__(256) void k_gemm(
    const __hip_bfloat16* __restrict__ A0,     // mean [n,128] bf16
    const __hip_bfloat16* __restrict__ A1,     // h    [n,128] bf16
    const __hip_bfloat16* __restrict__ Wb,     // [2][128][128] bf16: Wl then Wr
    const float* __restrict__ bias,            // [128] fp32
    float* __restrict__ outF,                  // fp32 output (or null)
    __hip_bfloat16* __restrict__ outB,         // bf16 output (or null)
    int n, int do_relu)
{
    __shared__ __hip_bfloat16 lW[2 * 128 * 128];   // 64 KB

    for (int g = threadIdx.x; g < 4096; g += 256) {
        int half = g >> 11;
        int rem  = g & 2047;
        int row  = rem >> 4;
        int c    = rem & 15;
        bf16x8 v = *(const bf16x8*)(Wb + half * 16384 + row * 128 + c * 8);
        *(bf16x8*)(lW + half * 16384 + row * 128 + ((c ^ (row & 7)) * 8)) = v;
    }
    __syncthreads();

    int w = threadIdx.x >> 6;
    int lane = threadIdx.x & 63;
    int m = lane & 15;
    int q = lane >> 4;
    int base = blockIdx.x * 256 + w * 64;      // this wave's 64 rows

    f32x4 acc[4][8];
    #pragma unroll
    for (int r = 0; r < 4; ++r)
        #pragma unroll
        for (int i = 0; i < 8; ++i) acc[r][i] = (f32x4){0.f, 0.f, 0.f, 0.f};

    const __hip_bfloat16* Aps[2] = {A0, A1};

    #pragma unroll
    for (int half = 0; half < 2; ++half) {
        const __hip_bfloat16* A = Aps[half];
        #pragma unroll
        for (int kk = 0; kk < 4; ++kk) {
            bf16x8 af[4];
            #pragma unroll
            for (int r = 0; r < 4; ++r) {
                int arow = base + r * 16 + m;
                if (arow > n - 1) arow = n - 1;     // clamp; masked at store
                af[r] = *(const bf16x8*)(A + (size_t)arow * D + kk * 32 + q * 8);
            }
            #pragma unroll
            for (int nt = 0; nt < 8; ++nt) {
                int row = nt * 16 + m;
                int c = (kk * 4 + q) ^ (m & 7);
                bf16x8 bf = *(const bf16x8*)(lW + half * 16384 + row * 128 + c * 8);
                #pragma unroll
                for (int r = 0; r < 4; ++r)
                    acc[r][nt] = __builtin_amdgcn_mfma_f32_16x16x32_bf16(af[r], bf, acc[r][nt], 0, 0, 0);
            }
        }
    }

    #pragma unroll
    for (int r = 0; r < 4; ++r) {
        #pragma unroll
        for (int nt = 0; nt < 8; ++nt) {
            int col = nt * 16 + m;
            float b = bias[col];
            #pragma unroll
            for (int rr = 0; rr < 4; ++rr) {
                int row = base + r * 16 + q * 4 + rr;
                if (row < n) {
                    float v = acc[r][nt][rr] + b;
                    if (do_relu) v = fmaxf(v, 0.f);
                    if (outF) outF[(size_t)row * D + col] = v;
                    else      outB[(size_t)row * D + col] = __float2bfloat16(v);
                }
            }
        }
    }
}

// ---------------- launch ----------------

extern "C" void kernel_launch(void* const* d_in, const int* in_sizes, int n_in,
                              void* d_out, int out_size, void* d_ws, size_t ws_size,
                              hipStream_t stream) {
    const float* x   = (const float*)d_in[0];
    const int*   ei  = (const int*)d_in[1];
    const float* Wl0 = (const float*)d_in[2];
    const float* bl0 = (const float*)d_in[3];
    const float* Wr0 = (const float*)d_in[4];
    const float* Wl1 = (const float*)d_in[5];
    const float* bl1 = (const float*)d_in[6];
    const float* Wr1 = (const float*)d_in[7];
    const float* Wl2 = (const float*)d_in[8];
    const float* bl2 = (const float*)d_in[9];
    const float* Wr2 = (const float*)d_in[10];

    const int n = in_sizes[0] / D;        // 100000
    const int e = in_sizes[1] / 2;        // 1600000
    const int* src = ei;
    const int* dst = ei + e;
    const int nb = (n + 255) >> 8;        // 391 buckets (must be <= 511)

    // workspace carve (256B aligned)
    uintptr_t p = ((uintptr_t)d_ws + 255) & ~(uintptr_t)255;
    auto carve = [&](size_t bytes) {
        uintptr_t r = p;
        p = (p + bytes + 255) & ~(uintptr_t)255;
        return (void*)r;
    };
    int* deg     = (int*)carve((size_t)n * 4);
    int* offs    = (int*)carve((size_t)n * 4);
    int* bhist   = (int*)carve(512 * 4);
    int* bbase   = (int*)carve(513 * 4);
    int* bcursor = (int*)carve(512 * 4);
    int* csr     = (int*)carve((size_t)e * 4);
    __hip_bfloat16* mean = (__hip_bfloat16*)carve((size_t)n * D * 2);   // 25.6 MB
    __hip_bfloat16* F1   = (__hip_bfloat16*)carve((size_t)n * D * 2);   // xb, later h1
    __hip_bfloat16* Wb   = (__hip_bfloat16*)carve((size_t)6 * D * D * 2); // 192 KB
    (void)ws_size; (void)n_in; (void)out_size;

    // d_out (51.2 MB fp32) moonlights: h0 (bf16) in first 25.6 MB, tmp (6.4 MB)
    // right after it — both dead before the final fp32 write.
    __hip_bfloat16* h0 = (__hip_bfloat16*)d_out;
    int* tmp = (int*)((char*)d_out + (size_t)n * D * 2);

    const int xpair = n * D / 2;          // 6.4M float2 pairs

    // ---- setup: zero bhist + all casts in ONE launch ----
    k_setup<<<(xpair + 255) / 256, 256, 0, stream>>>(
        x, Wl0, Wr0, Wl1, Wr1, Wl2, Wr2, F1, Wb, bhist, xpair);

    // ---- CSR build via bucket counting sort ----
    const int epb0 = (e + 511) / 512;
    k_p0<<<512, 256, 0, stream>>>(dst, bhist, e, n, epb0);
    k_bscan<<<1, 512, 0, stream>>>(bhist, bbase, bcursor, nb);
    const int epb1 = 8192;
    k_p1<<<(e + epb1 - 1) / epb1, 256, 0, stream>>>(src, dst, bcursor, tmp, e, n, epb1);
    k_p2<<<nb, 256, 0, stream>>>(tmp, bbase, deg, offs, csr, n);

    const int ag = (n + 3) / 4;           // wave per node
    const int gg = (n + 255) / 256;       // 256-node M-tiles

    __hip_bfloat16* Wb0 = Wb + 0 * 2 * D * D;
    __hip_bfloat16* Wb1 = Wb + 1 * 2 * D * D;
    __hip_bfloat16* Wb2 = Wb + 2 * 2 * D * D;

    // ---- layer 0: xb(F1) -> h0 (relu) ----
    k_agg<<<ag, 256, 0, stream>>>(F1, csr, offs, deg, mean, n);
    k_gemm<<<gg, 256, 0, stream>>>(mean, F1, Wb0, bl0, nullptr, h0, n, 1);
    // ---- layer 1: h0 -> h1(F1) (relu) ----
    k_agg<<<ag, 256, 0, stream>>>(h0, csr, offs, deg, mean, n);
    k_gemm<<<gg, 256, 0, stream>>>(mean, h0, Wb1, bl1, nullptr, F1, n, 1);
    // ---- layer 2: h1(F1) -> fp32 d_out (no relu) ----
    k_agg<<<ag, 256, 0, stream>>>(F1, csr, offs, deg, mean, n);
    k_gemm<<<gg, 256, 0, stream>>>(mean, F1, Wb2, bl2, (float*)d_out, nullptr, n, 0);
}

// Round 7
// 435.914 us; speedup vs baseline: 1.1036x; 1.1036x over previous
//
#include <hip/hip_runtime.h>
#include <hip/hip_bf16.h>

typedef __attribute__((ext_vector_type(8))) short bf16x8;   // 8 bf16 = 4 VGPRs
typedef __attribute__((ext_vector_type(4))) float f32x4;

#define D 128
#define P2CAP 8192

// ---------------- setup: zero bucket hist + cast x and all 6 weight matrices ----------------

__global__ __launch_bounds__(256) void k_setup(
    const float* __restrict__ x,
    const float* __restrict__ w0, const float* __restrict__ w1,
    const float* __restrict__ w2, const float* __restrict__ w3,
    const float* __restrict__ w4, const float* __restrict__ w5,
    __hip_bfloat16* __restrict__ xb, __hip_bfloat16* __restrict__ wb,
    int* __restrict__ bhist, int xpair)
{
    int t = blockIdx.x * 256 + threadIdx.x;
    if (t < 512) bhist[t] = 0;
    if (t < xpair) {
        float2 f = ((const float2*)x)[t];
        ((__hip_bfloat162*)xb)[t] = __float22bfloat162_rn(f);
    }
    if (t < 6 * 8192) {                      // 6 matrices x 8192 float2 pairs
        int wsel = t >> 13, wi = t & 8191;
        const float* wp = w0;
        if (wsel == 1) wp = w1;
        else if (wsel == 2) wp = w2;
        else if (wsel == 3) wp = w3;
        else if (wsel == 4) wp = w4;
        else if (wsel == 5) wp = w5;
        float2 f = ((const float2*)wp)[wi];
        ((__hip_bfloat162*)wb)[t] = __float22bfloat162_rn(f);
    }
}

// ---------------- CSR build: 2-level bucket counting sort ----------------
// bucket = dst >> 8 (256 nodes per bucket)

__global__ __launch_bounds__(256) void k_p0(const int* __restrict__ dst,
                                            int* __restrict__ bhist, int e, int n, int epb) {
    __shared__ int lh[512];
    for (int i = threadIdx.x; i < 512; i += 256) lh[i] = 0;
    __syncthreads();
    int lo = blockIdx.x * epb;
    int hi = lo + epb; if (hi > e) hi = e;
    for (int i = lo + threadIdx.x; i < hi; i += 256) {
        int d = dst[i]; d = ((unsigned)d < (unsigned)n) ? d : 0;
        atomicAdd(&lh[d >> 8], 1);
    }
    __syncthreads();
    for (int i = threadIdx.x; i < 512; i += 256)
        if (lh[i]) atomicAdd(&bhist[i], lh[i]);
}

__global__ void k_bscan(const int* __restrict__ bhist, int* __restrict__ bbase,
                        int* __restrict__ bcursor, int nb) {
    __shared__ int lds[512];
    int t = threadIdx.x;
    int v = (t < nb) ? bhist[t] : 0;
    lds[t] = v;
    __syncthreads();
    for (int off = 1; off < 512; off <<= 1) {
        int x = (t >= off) ? lds[t - off] : 0;
        __syncthreads();
        lds[t] += x;
        __syncthreads();
    }
    if (t < nb) { int b = lds[t] - v; bbase[t] = b; bcursor[t] = b; }
    if (t == nb) bbase[t] = lds[nb - 1];     // total
}

__global__ __launch_bounds__(256) void k_p1(const int* __restrict__ src,
                                            const int* __restrict__ dst,
                                            int* __restrict__ bcursor,
                                            int* __restrict__ tmp, int e, int n, int epb) {
    __shared__ int lh[512], gb[512];
    for (int i = threadIdx.x; i < 512; i += 256) lh[i] = 0;
    __syncthreads();
    int lo = blockIdx.x * epb;
    int hi = lo + epb; if (hi > e) hi = e;
    for (int i = lo + threadIdx.x; i < hi; i += 256) {
        int d = dst[i]; d = ((unsigned)d < (unsigned)n) ? d : 0;
        atomicAdd(&lh[d >> 8], 1);
    }
    __syncthreads();
    for (int i = threadIdx.x; i < 512; i += 256) {
        int c = lh[i];
        gb[i] = c ? atomicAdd(&bcursor[i], c) : 0;
    }
    __syncthreads();
    for (int i = threadIdx.x; i < 512; i += 256) lh[i] = 0;  // reuse as local cursor
    __syncthreads();
    for (int i = lo + threadIdx.x; i < hi; i += 256) {
        int d = dst[i]; d = ((unsigned)d < (unsigned)n) ? d : 0;
        int s = src[i]; s = ((unsigned)s < (unsigned)n) ? s : 0;
        int b = d >> 8;
        int p = gb[b] + atomicAdd(&lh[b], 1);
        tmp[p] = s | ((d & 255) << 17);      // src < 2^17, dlow in bits 17..24
    }
}

__global__ __launch_bounds__(256) void k_p2(const int* __restrict__ tmp,
                                            const int* __restrict__ bbase,
                                            int* __restrict__ deg, int* __restrict__ offs,
                                            int* __restrict__ csr, int n) {
    __shared__ int hist[256], loc[256], cur[256];
    __shared__ int out[P2CAP];
    int b = blockIdx.x, t = threadIdx.x;
    int base = bbase[b];
    int cnt = bbase[b + 1] - base;
    int nodes = n - b * 256; if (nodes > 256) nodes = 256;
    hist[t] = 0;
    __syncthreads();
    for (int i = t; i < cnt; i += 256)
        atomicAdd(&hist[(tmp[base + i] >> 17) & 255], 1);
    __syncthreads();
    int v = hist[t];
    loc[t] = v;
    __syncthreads();
    for (int off = 1; off < 256; off <<= 1) {
        int x = (t >= off) ? loc[t - off] : 0;
        __syncthreads();
        loc[t] += x;
        __syncthreads();
    }
    int myloc = loc[t] - v;                  // exclusive
    cur[t] = myloc;
    if (t < nodes) { deg[b * 256 + t] = v; offs[b * 256 + t] = base + myloc; }
    __syncthreads();
    if (cnt <= P2CAP) {
        for (int i = t; i < cnt; i += 256) {
            int e = tmp[base + i];
            int p = atomicAdd(&cur[(e >> 17) & 255], 1);
            out[p] = e & 0x1FFFF;
        }
        __syncthreads();
        for (int i = t; i < cnt; i += 256) csr[base + i] = out[i];   // coalesced
    } else {                                  // slow-path fallback (never for uniform edges)
        for (int i = t; i < cnt; i += 256) {
            int e = tmp[base + i];
            int p = atomicAdd(&cur[(e >> 17) & 255], 1);
            csr[base + p] = e & 0x1FFFF;
        }
    }
}

// ---------------- mean aggregation: wave per node ----------------
// 4 lane-groups x 16 lanes x 16B; bulk loop does 16 edges/iter with 4
// independent 1KB gathers in flight (no masks); one masked tail iteration.

__device__ __forceinline__ void acc_int4(float* acc, int4 d) {
    acc[0] += __uint_as_float((unsigned)d.x << 16);
    acc[1] += __uint_as_float((unsigned)d.x & 0xffff0000u);
    acc[2] += __uint_as_float((unsigned)d.y << 16);
    acc[3] += __uint_as_float((unsigned)d.y & 0xffff0000u);
    acc[4] += __uint_as_float((unsigned)d.z << 16);
    acc[5] += __uint_as_float((unsigned)d.z & 0xffff0000u);
    acc[6] += __uint_as_float((unsigned)d.w << 16);
    acc[7] += __uint_as_float((unsigned)d.w & 0xffff0000u);
}

__global__ __launch_bounds__(256) void k_agg(
    const __hip_bfloat16* __restrict__ h,      // [n, 128]
    const int* __restrict__ csr,
    const int* __restrict__ offs,
    const int* __restrict__ deg,
    __hip_bfloat16* __restrict__ mean,         // [n, 128]
    int n)
{
    int node = blockIdx.x * 4 + (threadIdx.x >> 6);
    int lane = threadIdx.x & 63;
    if (node >= n) return;
    int grp = lane >> 4;                       // edge slot 0..3
    int sub = lane & 15;                       // 16B chunk within the 256B row
    int start = offs[node];
    int cnt = deg[node];

    float acc[8];
    #pragma unroll
    for (int k = 0; k < 8; ++k) acc[k] = 0.f;

    const char* hb = (const char*)h;
    int i = 0;
    int bulk = cnt & ~15;

    // bulk: 16 edges per iter, 4 independent gathers, no masking
    for (; i < bulk; i += 16) {
        int4 d[4];
        #pragma unroll
        for (int u = 0; u < 4; ++u) {
            int s = csr[start + i + u * 4 + grp];
            s = ((unsigned)s < (unsigned)n) ? s : 0;
            d[u] = *(const int4*)(hb + (size_t)s * 256 + sub * 16);
        }
        #pragma unroll
        for (int u = 0; u < 4; ++u) acc_int4(acc, d[u]);
    }

    // masked tail: up to 15 edges
    if (i < cnt) {
        int4 d[4];
        #pragma unroll
        for (int u = 0; u < 4; ++u) {
            int e = i + u * 4 + grp;
            int ec = (e < cnt) ? e : (cnt - 1);    // valid address (cnt >= 1 here)
            int s = csr[start + ec];
            s = ((unsigned)s < (unsigned)n) ? s : 0;
            d[u] = *(const int4*)(hb + (size_t)s * 256 + sub * 16);
            if (e >= cnt) { d[u].x = 0; d[u].y = 0; d[u].z = 0; d[u].w = 0; }
        }
        #pragma unroll
        for (int u = 0; u < 4; ++u) acc_int4(acc, d[u]);
    }

    // reduce across the 4 edge groups (lanes differing in bits 4..5)
    #pragma unroll
    for (int k = 0; k < 8; ++k) {
        acc[k] += __shfl_xor(acc[k], 16);
        acc[k] += __shfl_xor(acc[k], 32);
    }

    if (grp == 0) {
        float inv = 1.0f / fmaxf((float)cnt, 1.0f);
        union { int4 i4; __hip_bfloat162 h2[4]; } u;
        #pragma unroll
        for (int k = 0; k < 4; ++k)
            u.h2[k] = __float22bfloat162_rn(make_float2(acc[2 * k] * inv, acc[2 * k + 1] * inv));
        *(int4*)((char*)mean + (size_t)node * 256 + sub * 16) = u.i4;
    }
}

// ---------------- fused GEMM: out = act([mean|h] @ [Wl|Wr]^T + b) ----------------
// Block: 256 threads = 4 waves, M-tile = 256 rows (64/wave = 4 MFMA row-tiles).
// W (both halves, 64 KB) in LDS, XOR-swizzled 16B chunks; each B-fragment
// LDS read feeds 4 MFMAs.

__global__ __launch_bounds__(256) void k_gemm(
    const __hip_bfloat16* __restrict__ A0,     // mean [n,128] bf16
    const __hip_bfloat16* __restrict__ A1,     // h    [n,128] bf16
    const __hip_bfloat16* __restrict__ Wb,     // [2][128][128] bf16: Wl then Wr
    const float* __restrict__ bias,            // [128] fp32
    float* __restrict__ outF,                  // fp32 output (or null)
    __hip_bfloat16* __restrict__ outB,         // bf16 output (or null)
    int n, int do_relu)
{
    __shared__ __hip_bfloat16 lW[2 * 128 * 128];   // 64 KB

    for (int g = threadIdx.x; g < 4096; g += 256) {
        int half = g >> 11;
        int rem  = g & 2047;
        int row  = rem >> 4;
        int c    = rem & 15;
        bf16x8 v = *(const bf16x8*)(Wb + half * 16384 + row * 128 + c * 8);
        *(bf16x8*)(lW + half * 16384 + row * 128 + ((c ^ (row & 7)) * 8)) = v;
    }
    __syncthreads();

    int w = threadIdx.x >> 6;
    int lane = threadIdx.x & 63;
    int m = lane & 15;
    int q = lane >> 4;
    int base = blockIdx.x * 256 + w * 64;      // this wave's 64 rows

    f32x4 acc[4][8];
    #pragma unroll
    for (int r = 0; r < 4; ++r)
        #pragma unroll
        for (int i = 0; i < 8; ++i) acc[r][i] = (f32x4){0.f, 0.f, 0.f, 0.f};

    const __hip_bfloat16* Aps[2] = {A0, A1};

    #pragma unroll
    for (int half = 0; half < 2; ++half) {
        const __hip_bfloat16* A = Aps[half];
        #pragma unroll
        for (int kk = 0; kk < 4; ++kk) {
            bf16x8 af[4];
            #pragma unroll
            for (int r = 0; r < 4; ++r) {
                int arow = base + r * 16 + m;
                if (arow > n - 1) arow = n - 1;     // clamp; masked at store
                af[r] = *(const bf16x8*)(A + (size_t)arow * D + kk * 32 + q * 8);
            }
            #pragma unroll
            for (int nt = 0; nt < 8; ++nt) {
                int row = nt * 16 + m;
                int c = (kk * 4 + q) ^ (m & 7);
                bf16x8 bf = *(const bf16x8*)(lW + half * 16384 + row * 128 + c * 8);
                #pragma unroll
                for (int r = 0; r < 4; ++r)
                    acc[r][nt] = __builtin_amdgcn_mfma_f32_16x16x32_bf16(af[r], bf, acc[r][nt], 0, 0, 0);
            }
        }
    }

    #pragma unroll
    for (int r = 0; r < 4; ++r) {
        #pragma unroll
        for (int nt = 0; nt < 8; ++nt) {
            int col = nt * 16 + m;
            float b = bias[col];
            #pragma unroll
            for (int rr = 0; rr < 4; ++rr) {
                int row = base + r * 16 + q * 4 + rr;
                if (row < n) {
                    float v = acc[r][nt][rr] + b;
                    if (do_relu) v = fmaxf(v, 0.f);
                    if (outF) outF[(size_t)row * D + col] = v;
                    else      outB[(size_t)row * D + col] = __float2bfloat16(v);
                }
            }
        }
    }
}

// ---------------- launch ----------------

extern "C" void kernel_launch(void* const* d_in, const int* in_sizes, int n_in,
                              void* d_out, int out_size, void* d_ws, size_t ws_size,
                              hipStream_t stream) {
    const float* x   = (const float*)d_in[0];
    const int*   ei  = (const int*)d_in[1];
    const float* Wl0 = (const float*)d_in[2];
    const float* bl0 = (const float*)d_in[3];
    const float* Wr0 = (const float*)d_in[4];
    const float* Wl1 = (const float*)d_in[5];
    const float* bl1 = (const float*)d_in[6];
    const float* Wr1 = (const float*)d_in[7];
    const float* Wl2 = (const float*)d_in[8];
    const float* bl2 = (const float*)d_in[9];
    const float* Wr2 = (const float*)d_in[10];

    const int n = in_sizes[0] / D;        // 100000
    const int e = in_sizes[1] / 2;        // 1600000
    const int* src = ei;
    const int* dst = ei + e;
    const int nb = (n + 255) >> 8;        // 391 buckets (must be <= 511)

    // workspace carve (256B aligned)
    uintptr_t p = ((uintptr_t)d_ws + 255) & ~(uintptr_t)255;
    auto carve = [&](size_t bytes) {
        uintptr_t r = p;
        p = (p + bytes + 255) & ~(uintptr_t)255;
        return (void*)r;
    };
    int* deg     = (int*)carve((size_t)n * 4);
    int* offs    = (int*)carve((size_t)n * 4);
    int* bhist   = (int*)carve(512 * 4);
    int* bbase   = (int*)carve(513 * 4);
    int* bcursor = (int*)carve(512 * 4);
    int* csr     = (int*)carve((size_t)e * 4);
    __hip_bfloat16* mean = (__hip_bfloat16*)carve((size_t)n * D * 2);   // 25.6 MB
    __hip_bfloat16* F1   = (__hip_bfloat16*)carve((size_t)n * D * 2);   // xb, later h1
    __hip_bfloat16* Wb   = (__hip_bfloat16*)carve((size_t)6 * D * D * 2); // 192 KB
    (void)ws_size; (void)n_in; (void)out_size;

    // d_out (51.2 MB fp32) moonlights: h0 (bf16) in first 25.6 MB, tmp (6.4 MB)
    // right after it — both dead before the final fp32 write.
    __hip_bfloat16* h0 = (__hip_bfloat16*)d_out;
    int* tmp = (int*)((char*)d_out + (size_t)n * D * 2);

    const int xpair = n * D / 2;          // 6.4M float2 pairs

    // ---- setup: zero bhist + all casts in ONE launch ----
    k_setup<<<(xpair + 255) / 256, 256, 0, stream>>>(
        x, Wl0, Wr0, Wl1, Wr1, Wl2, Wr2, F1, Wb, bhist, xpair);

    // ---- CSR build via bucket counting sort ----
    const int epb0 = (e + 511) / 512;
    k_p0<<<512, 256, 0, stream>>>(dst, bhist, e, n, epb0);
    k_bscan<<<1, 512, 0, stream>>>(bhist, bbase, bcursor, nb);
    const int epb1 = 8192;
    k_p1<<<(e + epb1 - 1) / epb1, 256, 0, stream>>>(src, dst, bcursor, tmp, e, n, epb1);
    k_p2<<<nb, 256, 0, stream>>>(tmp, bbase, deg, offs, csr, n);

    const int ag = (n + 3) / 4;           // wave per node
    const int gg = (n + 255) / 256;       // 256-node M-tiles

    __hip_bfloat16* Wb0 = Wb + 0 * 2 * D * D;
    __hip_bfloat16* Wb1 = Wb + 1 * 2 * D * D;
    __hip_bfloat16* Wb2 = Wb + 2 * 2 * D * D;

    // ---- layer 0: xb(F1) -> h0 (relu) ----
    k_agg<<<ag, 256, 0, stream>>>(F1, csr, offs, deg, mean, n);
    k_gemm<<<gg, 256, 0, stream>>>(mean, F1, Wb0, bl0, nullptr, h0, n, 1);
    // ---- layer 1: h0 -> h1(F1) (relu) ----
    k_agg<<<ag, 256, 0, stream>>>(h0, csr, offs, deg, mean, n);
    k_gemm<<<gg, 256, 0, stream>>>(mean, h0, Wb1, bl1, nullptr, F1, n, 1);
    // ---- layer 2: h1(F1) -> fp32 d_out (no relu) ----
    k_agg<<<ag, 256, 0, stream>>>(F1, csr, offs, deg, mean, n);
    k_gemm<<<gg, 256, 0, stream>>>(mean, F1, Wb2, bl2, (float*)d_out, nullptr, n, 0);
}